// Round 5
// baseline (322.214 us; speedup 1.0000x reference)
//
#include <hip/hip_runtime.h>
#include <hip/hip_bf16.h>

// Single-head causal attention. fp32 in, fp32 out. B=4, T=4096, C=2048, HS=128.
//
// R10: R9's z-fused QKV GEMM with the V^T epilogue bug fixed. R9 wrote only
// half the vT tile (512 ids = 128 rows x 4 chunks; need 1024 ids = 128 x 8).
// Fix: two-iteration writeout id = i*512 + t. Everything else as R9:
//  - 512-thread blocks, GBM=64, grid=256 = exactly 1 block/CU, 8 waves.
//  - All 3 z computed per block: X staged once (was 3x), Ws holds 3 W tiles.
//  - Double-buffered LDS (126 KB) -> ONE barrier per K-step (was 2).
//  - Register-prefetch for the next K-step's X+W.
//  - Epilogue writes Q, K, and V^T (LDS-transposed) directly.
// Flash / merge / wtrans unchanged from R8.

#define B_  4
#define T_  4096
#define C_  2048
#define HS_ 128

typedef unsigned short u16;
typedef __attribute__((ext_vector_type(8))) short short8;
typedef __attribute__((ext_vector_type(4))) float floatx4;

static __device__ __forceinline__ u16 f2bf(float x) {
  union { float f; unsigned u; } c; c.f = x;
  unsigned r = 0x7fffu + ((c.u >> 16) & 1u);
  return (u16)((c.u + r) >> 16);
}

// ---------------------------------------------------------------- W^T (x3)
__global__ __launch_bounds__(256) void wtrans3_kernel(
    const float* __restrict__ Wq, const float* __restrict__ Wk,
    const float* __restrict__ Wv, u16* __restrict__ dst) {
  __shared__ u16 tile[32][33];
  int z = blockIdx.z;
  const float* src = (z == 0) ? Wq : (z == 1) ? Wk : Wv;
  u16* d = dst + (size_t)z * HS_ * C_;
  int c0 = blockIdx.x * 32, r0 = blockIdx.y * 32;  // c over HS_, r over C_
  int tx = threadIdx.x, ty = threadIdx.y;          // block (32, 8)
#pragma unroll
  for (int i = 0; i < 4; ++i)
    tile[ty + 8 * i][tx] = f2bf(src[(size_t)(r0 + ty + 8 * i) * HS_ + (c0 + tx)]);
  __syncthreads();
#pragma unroll
  for (int i = 0; i < 4; ++i)
    d[(size_t)(c0 + ty + 8 * i) * C_ + (r0 + tx)] = tile[tx][ty + 8 * i];
}

// ---------------------------------------------------------------- QKV GEMM (fused z)
#define GBM 64
#define GBK 64
#define NKT (C_ / GBK)

__global__ __launch_bounds__(512) void qkv_gemm_fused(
    const float* __restrict__ X, const u16* __restrict__ WT3,
    u16* __restrict__ qkv, u16* __restrict__ vT) {
  // double-buffered staging: per buffer Xs[64][72] + Ws[384][72] (z-major W)
  __shared__ u16 Xs[2][GBM][72];
  __shared__ u16 Ws[2][3 * HS_][72];

  int t = threadIdx.x;                     // 0..511, 8 waves
  int wv = t >> 6, lane = t & 63;
  int l15 = lane & 15, hi = lane >> 4;
  int wm = (wv & 1) * 32;                  // M half (64 = 2x32)
  int wn = (wv >> 1) * 32;                 // N quarter (128 = 4x32)
  size_t mbase = (size_t)blockIdx.x * GBM;

  // staging decomposition: row xm (0..63), 8-col chunk xc (0..7)
  int xm = t >> 3, xc = t & 7;
  const float* xrow = &X[(mbase + xm) * C_];
  const u16* wb[6];
#pragma unroll
  for (int j = 0; j < 6; ++j) {
    int g = xm + 64 * j;                   // 0..383 over (z,row)
    wb[j] = &WT3[(size_t)(g >> 7) * HS_ * C_ + (size_t)(g & 127) * C_];
  }

  floatx4 acc[3][2][2];
#pragma unroll
  for (int z = 0; z < 3; ++z)
#pragma unroll
    for (int i = 0; i < 2; ++i)
#pragma unroll
      for (int j = 0; j < 2; ++j) acc[z][i][j] = (floatx4){0.f, 0.f, 0.f, 0.f};

  floatx4 xreg[2];
  short8 wreg[6];

  // prefetch kt=0
  {
    int koff = xc * 8;
    xreg[0] = *(const floatx4*)&xrow[koff];
    xreg[1] = *(const floatx4*)&xrow[koff + 4];
#pragma unroll
    for (int j = 0; j < 6; ++j) wreg[j] = *(const short8*)&wb[j][koff];
  }
  // stage into buffer 0
  {
    short8 xv;
#pragma unroll
    for (int j = 0; j < 4; ++j) {
      xv[j] = (short)f2bf(xreg[0][j]);
      xv[4 + j] = (short)f2bf(xreg[1][j]);
    }
    *(short8*)&Xs[0][xm][xc * 8] = xv;
#pragma unroll
    for (int j = 0; j < 6; ++j) *(short8*)&Ws[0][xm + 64 * j][xc * 8] = wreg[j];
  }
  __syncthreads();

  for (int kt = 0; kt < NKT; ++kt) {
    int p = kt & 1;
    // issue next K-step's global loads; latency hides under MFMA phase
    if (kt + 1 < NKT) {
      int koff = (kt + 1) * GBK + xc * 8;
      xreg[0] = *(const floatx4*)&xrow[koff];
      xreg[1] = *(const floatx4*)&xrow[koff + 4];
#pragma unroll
      for (int j = 0; j < 6; ++j) wreg[j] = *(const short8*)&wb[j][koff];
    }

    // MFMA phase on buffer p
#pragma unroll
    for (int ks = 0; ks < 2; ++ks) {
      short8 af[2];
#pragma unroll
      for (int mt = 0; mt < 2; ++mt)
        af[mt] = *(const short8*)&Xs[p][wm + mt * 16 + l15][ks * 32 + hi * 8];
#pragma unroll
      for (int z = 0; z < 3; ++z)
#pragma unroll
        for (int nt = 0; nt < 2; ++nt) {
          short8 bfrag =
              *(const short8*)&Ws[p][z * HS_ + wn + nt * 16 + l15][ks * 32 + hi * 8];
#pragma unroll
          for (int mt = 0; mt < 2; ++mt)
            acc[z][mt][nt] = __builtin_amdgcn_mfma_f32_16x16x32_bf16(
                af[mt], bfrag, acc[z][mt][nt], 0, 0, 0);
        }
    }

    // stage prefetched regs into the other buffer (waits vmcnt internally)
    if (kt + 1 < NKT) {
      short8 xv;
#pragma unroll
      for (int j = 0; j < 4; ++j) {
        xv[j] = (short)f2bf(xreg[0][j]);
        xv[4 + j] = (short)f2bf(xreg[1][j]);
      }
      *(short8*)&Xs[p ^ 1][xm][xc * 8] = xv;
#pragma unroll
      for (int j = 0; j < 6; ++j)
        *(short8*)&Ws[p ^ 1][xm + 64 * j][xc * 8] = wreg[j];
    }
    __syncthreads();
  }

  const size_t qkvsz = (size_t)B_ * T_ * HS_;
  // Q, K epilogue (z = 0, 1)
#pragma unroll
  for (int z = 0; z < 2; ++z) {
    u16* outp = qkv + (size_t)z * qkvsz;
#pragma unroll
    for (int mt = 0; mt < 2; ++mt)
#pragma unroll
      for (int nt = 0; nt < 2; ++nt)
#pragma unroll
        for (int r = 0; r < 4; ++r) {
          size_t row = mbase + wm + mt * 16 + hi * 4 + r;
          int col = wn + nt * 16 + l15;
          outp[row * HS_ + col] = f2bf(acc[z][mt][nt][r]);
        }
  }

  // V^T epilogue: transpose 64x128 tile in LDS (reuse Ws[0]), write vT.
  u16 (*Tb)[72] = (u16(*)[72])Ws[0];       // [128][72] region
#pragma unroll
  for (int mt = 0; mt < 2; ++mt)
#pragma unroll
    for (int nt = 0; nt < 2; ++nt)
#pragma unroll
      for (int r = 0; r < 4; ++r)
        Tb[wn + nt * 16 + l15][wm + mt * 16 + hi * 4 + r] = f2bf(acc[2][mt][nt][r]);
  __syncthreads();
  {
    int b = (int)(mbase >> 12);            // T_ = 4096
    int trow0 = (int)(mbase & (T_ - 1));
    u16* vb = vT + (size_t)b * HS_ * T_;
#pragma unroll
    for (int i = 0; i < 2; ++i) {
      int id = i * 512 + t;                // 1024 ids = 128 rows x 8 chunks
      int c = id >> 3, ch = id & 7;
      short8 v = *(const short8*)&Tb[c][ch * 8];
      *(short8*)&vb[(size_t)c * T_ + trow0 + ch * 8] = v;
    }
  }
}

// ---------------------------------------------------------------- flash core
#define BQ 64
#define BKV 64
#define CHUNK 16  // KV tiles per split-KV block (1024 keys)

// Shared body: processes kv tiles [kb0, kb1] for (b, qb). If WRITE_PARTIAL,
// writes unnormalized O + (m,l); else normalizes and writes fp32 out.
template <bool WRITE_PARTIAL>
static __device__ __forceinline__ void flash_body(
    const u16* __restrict__ q, const u16* __restrict__ k,
    const u16* __restrict__ vT, float* __restrict__ outO,
    float* __restrict__ Mp, float* __restrict__ Lp,
    int b, int qb, int kb0, int kb1, int slot) {
  __shared__ u16 Ks[BKV][136];
  __shared__ u16 Vs[144][72];   // rows 0..127: V^T tile; rows 128..143: ones (l-column)
  __shared__ u16 Ps[BQ][72];
  int t = threadIdx.x;
  int wv = t >> 6, lane = t & 63, l15 = lane & 15, hi = lane >> 4;

  const float sc = 0.08838834764831845f * 1.4426950408889634f;

  short8 qf[4];
  {
    const u16* qrow = q + (size_t)(b * T_ + qb * BQ + wv * 16 + l15) * HS_;
#pragma unroll
    for (int ks = 0; ks < 4; ++ks)
      qf[ks] = *(const short8*)(qrow + ks * 32 + hi * 8);
  }

  // ones rows for MFMA l-accumulation: rows 128..143, cols 0..63 used by PV.
  {
    int r = 128 + (t >> 4), c0 = (t & 15) * 4;
    const u16 one = 0x3F80;  // bf16 1.0
    Vs[r][c0] = one; Vs[r][c0 + 1] = one;
    Vs[r][c0 + 2] = one; Vs[r][c0 + 3] = one;
  }

  floatx4 of[9];  // of[0..7] = O; of[8] = l (row-sum column)
#pragma unroll
  for (int dt = 0; dt < 9; ++dt) of[dt] = (floatx4){0.f, 0.f, 0.f, 0.f};
  float m_run[4];
#pragma unroll
  for (int r = 0; r < 4; ++r) m_run[r] = -__builtin_inff();

  const u16* kbase = k + (size_t)b * T_ * HS_;
  const u16* vbase = vT + (size_t)b * HS_ * T_;

  // ---- register prefetch of tile kb0
  short8 kreg[4], vreg[4];
#pragma unroll
  for (int i = 0; i < 4; ++i) {
    int id = i * 256 + t;
    int n = id >> 4, ck = id & 15;
    kreg[i] = *(const short8*)&kbase[(size_t)(kb0 * BKV + n) * HS_ + ck * 8];
    int d = id >> 3, cv = id & 7;
    vreg[i] = *(const short8*)&vbase[(size_t)d * T_ + kb0 * BKV + cv * 8];
  }

  for (int kb = kb0; kb <= kb1; ++kb) {
    // write staged registers -> LDS (vmcnt wait inserted by compiler)
#pragma unroll
    for (int i = 0; i < 4; ++i) {
      int id = i * 256 + t;
      int n = id >> 4, ck = id & 15;
      *(short8*)&Ks[n][ck * 8] = kreg[i];
      int d = id >> 3, cv = id & 7;
      *(short8*)&Vs[d][cv * 8] = vreg[i];
    }
    __syncthreads();

    // issue next tile's global loads early; results not needed until next
    // loop top, so their latency hides under QK/softmax/PV below.
    if (kb < kb1) {
#pragma unroll
      for (int i = 0; i < 4; ++i) {
        int id = i * 256 + t;
        int n = id >> 4, ck = id & 15;
        kreg[i] = *(const short8*)&kbase[(size_t)((kb + 1) * BKV + n) * HS_ + ck * 8];
        int d = id >> 3, cv = id & 7;
        vreg[i] = *(const short8*)&vbase[(size_t)d * T_ + (kb + 1) * BKV + cv * 8];
      }
    }

    floatx4 sf[4];
#pragma unroll
    for (int nt = 0; nt < 4; ++nt) {
      floatx4 s = (floatx4){0.f, 0.f, 0.f, 0.f};
#pragma unroll
      for (int ks = 0; ks < 4; ++ks) {
        short8 bfrag = *(const short8*)&Ks[nt * 16 + l15][ks * 32 + hi * 8];
        s = __builtin_amdgcn_mfma_f32_16x16x32_bf16(qf[ks], bfrag, s, 0, 0, 0);
      }
      sf[nt] = s;
    }

    float sv[4][4];
    if (kb == qb) {
#pragma unroll
      for (int nt = 0; nt < 4; ++nt) {
        int col = nt * 16 + l15;
#pragma unroll
        for (int r = 0; r < 4; ++r) {
          int row = wv * 16 + hi * 4 + r;
          sv[nt][r] = (col <= row) ? sf[nt][r] * sc : -__builtin_inff();
        }
      }
    } else {
#pragma unroll
      for (int nt = 0; nt < 4; ++nt)
#pragma unroll
        for (int r = 0; r < 4; ++r) sv[nt][r] = sf[nt][r] * sc;
    }

    // per-row max (4-step butterfly over the 16-lane group)
    float mt4[4];
#pragma unroll
    for (int r = 0; r < 4; ++r)
      mt4[r] = fmaxf(fmaxf(sv[0][r], sv[1][r]), fmaxf(sv[2][r], sv[3][r]));
#pragma unroll
    for (int off = 1; off < 16; off <<= 1)
#pragma unroll
      for (int r = 0; r < 4; ++r)
        mt4[r] = fmaxf(mt4[r], __shfl_xor(mt4[r], off));

    // defer-max: only rescale when a row max grew by > 8 (P bounded by 2^8)
    bool need = false;
#pragma unroll
    for (int r = 0; r < 4; ++r) need = need || (mt4[r] > m_run[r] + 8.f);
    if (__any(need)) {
      float alpha[4];
#pragma unroll
      for (int r = 0; r < 4; ++r) {
        float mn = fmaxf(m_run[r], mt4[r]);
        alpha[r] = exp2f(m_run[r] - mn);
        m_run[r] = mn;
      }
#pragma unroll
      for (int dt = 0; dt < 9; ++dt)
#pragma unroll
        for (int r = 0; r < 4; ++r) of[dt][r] *= alpha[r];
    }

    float pv[4][4];
#pragma unroll
    for (int nt = 0; nt < 4; ++nt)
#pragma unroll
      for (int r = 0; r < 4; ++r) pv[nt][r] = exp2f(sv[nt][r] - m_run[r]);

#pragma unroll
    for (int nt = 0; nt < 4; ++nt)
#pragma unroll
      for (int r = 0; r < 4; ++r)
        Ps[wv * 16 + hi * 4 + r][nt * 16 + l15] = f2bf(pv[nt][r]);
    __asm__ volatile("s_waitcnt lgkmcnt(0)" ::: "memory");

#pragma unroll
    for (int ks2 = 0; ks2 < 2; ++ks2) {
      short8 af = *(const short8*)&Ps[wv * 16 + l15][ks2 * 32 + hi * 8];
#pragma unroll
      for (int dt = 0; dt < 9; ++dt) {
        short8 bfrag = *(const short8*)&Vs[dt * 16 + l15][ks2 * 32 + hi * 8];
        of[dt] = __builtin_amdgcn_mfma_f32_16x16x32_bf16(af, bfrag, of[dt], 0, 0, 0);
      }
    }
    __syncthreads();
  }

  if (WRITE_PARTIAL) {
    float* Op = outO + (size_t)slot * (BQ * HS_);
#pragma unroll
    for (int dt = 0; dt < 8; ++dt)
#pragma unroll
      for (int r = 0; r < 4; ++r) {
        int row = wv * 16 + hi * 4 + r;
        Op[row * HS_ + dt * 16 + l15] = of[dt][r];
      }
    if (l15 == 0) {
#pragma unroll
      for (int r = 0; r < 4; ++r) {
        int row = wv * 16 + hi * 4 + r;
        Mp[slot * BQ + row] = m_run[r];
        Lp[slot * BQ + row] = of[8][r];  // l accumulated by MFMA ones-column
      }
    }
  } else {
    float rl[4];
#pragma unroll
    for (int r = 0; r < 4; ++r) rl[r] = 1.0f / of[8][r];
#pragma unroll
    for (int dt = 0; dt < 8; ++dt)
#pragma unroll
      for (int r = 0; r < 4; ++r) {
        size_t row = (size_t)(b * T_ + qb * BQ + wv * 16 + hi * 4 + r);
        outO[row * HS_ + dt * 16 + l15] = of[dt][r] * rl[r];
      }
  }
}

// split-KV partial: grid (64 qb, 4 chunk, 4 batch)
__global__ __launch_bounds__(256, 3) void flash_partial_kernel(
    const u16* __restrict__ q, const u16* __restrict__ k,
    const u16* __restrict__ vT, float* __restrict__ Opart,
    float* __restrict__ Mpart, float* __restrict__ Lpart) {
  int qb = blockIdx.x, c = blockIdx.y, b = blockIdx.z;
  int kb0 = c * CHUNK;
  if (kb0 > qb) return;  // empty chunk
  int kb1 = min(qb, kb0 + CHUNK - 1);
  int slot = (b * (T_ / BQ) + qb) * 4 + c;
  flash_body<true>(q, k, vT, Opart, Mpart, Lpart, b, qb, kb0, kb1, slot);
}

// monolithic fallback: grid (64 qb, 4 batch)
__global__ __launch_bounds__(256, 3) void flash_attn_kernel(
    const u16* __restrict__ q, const u16* __restrict__ k,
    const u16* __restrict__ vT, float* __restrict__ out) {
  int qb = blockIdx.x, b = blockIdx.y;
  flash_body<false>(q, k, vT, out, nullptr, nullptr, b, qb, 0, qb, 0);
}

// merge: grid (64 qb, 4 batch), 256 threads
__global__ __launch_bounds__(256) void flash_merge_kernel(
    const float* __restrict__ Opart, const float* __restrict__ Mpart,
    const float* __restrict__ Lpart, float* __restrict__ out) {
  __shared__ float w[4][BQ];
  __shared__ float invL[BQ];
  int qb = blockIdx.x, b = blockIdx.y;
  int t = threadIdx.x;
  int nch = qb / CHUNK + 1;  // 1..4
  int slot0 = (b * (T_ / BQ) + qb) * 4;

  if (t < BQ) {
    float mv[4], mmax = -__builtin_inff();
    for (int c = 0; c < nch; ++c) {
      mv[c] = Mpart[(slot0 + c) * BQ + t];
      mmax = fmaxf(mmax, mv[c]);
    }
    float L = 0.f;
    for (int c = 0; c < nch; ++c) {
      float wc = exp2f(mv[c] - mmax);
      w[c][t] = wc;
      L += wc * Lpart[(slot0 + c) * BQ + t];
    }
    invL[t] = 1.0f / L;
  }
  __syncthreads();

  size_t obase = ((size_t)(b * T_) + (size_t)qb * BQ) * HS_;
#pragma unroll
  for (int j = 0; j < 32; ++j) {
    int e = j * 256 + t;           // 0..8191
    int row = e >> 7;
    float acc = 0.f;
    for (int c = 0; c < nch; ++c)
      acc += w[c][row] * Opart[(size_t)(slot0 + c) * (BQ * HS_) + e];
    out[obase + e] = acc * invL[row];
  }
}

// ---------------------------------------------------------------- launch
extern "C" void kernel_launch(void* const* d_in, const int* in_sizes, int n_in,
                              void* d_out, int out_size, void* d_ws, size_t ws_size,
                              hipStream_t stream) {
  const float* x  = (const float*)d_in[0];
  const float* Wq = (const float*)d_in[1];
  const float* Wk = (const float*)d_in[2];
  const float* Wv = (const float*)d_in[3];
  float* out = (float*)d_out;

  u16* ws = (u16*)d_ws;
  const size_t wtsz  = (size_t)HS_ * C_;
  const size_t qkvsz = (size_t)B_ * T_ * HS_;
  u16* WT = ws;
  u16* qv = WT + 3 * wtsz;
  u16* kv = qv + qkvsz;
  u16* vT = kv + qkvsz;
  const size_t base_bytes = (3 * wtsz + 3 * qkvsz) * sizeof(u16);  // 14,155,776

  const int NSLOT = B_ * (T_ / BQ) * 4;  // 1024
  float* Opart = (float*)((char*)d_ws + base_bytes);
  float* Mpart = Opart + (size_t)NSLOT * BQ * HS_;
  float* Lpart = Mpart + (size_t)NSLOT * BQ;
  const size_t split_bytes =
      base_bytes + ((size_t)NSLOT * BQ * HS_ + 2 * (size_t)NSLOT * BQ) * sizeof(float);

  dim3 tb(32, 8);
  wtrans3_kernel<<<dim3(HS_ / 32, C_ / 32, 3), tb, 0, stream>>>(Wq, Wk, Wv, WT);

  qkv_gemm_fused<<<dim3((B_ * T_) / GBM), 512, 0, stream>>>(x, WT, qv, vT);

  if (ws_size >= split_bytes) {
    flash_partial_kernel<<<dim3(T_ / BQ, 4, B_), 256, 0, stream>>>(
        qv, kv, vT, Opart, Mpart, Lpart);
    flash_merge_kernel<<<dim3(T_ / BQ, B_), 256, 0, stream>>>(
        Opart, Mpart, Lpart, out);
  } else {
    flash_attn_kernel<<<dim3(T_ / BQ, B_), 256, 0, stream>>>(qv, kv, vT, out);
  }
}

// Round 6
// 322.208 us; speedup vs baseline: 1.0000x; 1.0000x over previous
//
#include <hip/hip_runtime.h>
#include <hip/hip_bf16.h>

// Single-head causal attention. fp32 in, fp32 out. B=4, T=4096, C=2048, HS=128.
//
// R11: GEMM re-tiled for LDS-read-pipe efficiency. R10 post-mortem: fused
// GEMM was LDS-read-bound (8 ds_read : 12 MFMA per wave-ks, ratio 1.33;
// ~1540 cy/kt on the LDS pipe vs 230 cy MFMA). Changes:
//  - Un-fuse z (X re-reads are L3-absorbed; fusion only helped VALU).
//  - BM=128 x BN=128 tiles, 256 threads, 4 waves, each wave 64x64 output
//    (4x4 frags): 8 ds_read : 16 MFMA per ks -> ratio 2.0.
//  - Double-buffered LDS 72 KB -> 2 blocks/CU. Grid 128x3.
//  - Reg-prefetch K-loop (R6-proven), one barrier per K-step.
//  - V^T fused epilogue kept (z==2 transposes its 128x128 tile in LDS).
// Flash / merge / wtrans unchanged.

#define B_  4
#define T_  4096
#define C_  2048
#define HS_ 128

typedef unsigned short u16;
typedef __attribute__((ext_vector_type(8))) short short8;
typedef __attribute__((ext_vector_type(4))) float floatx4;

static __device__ __forceinline__ u16 f2bf(float x) {
  union { float f; unsigned u; } c; c.f = x;
  unsigned r = 0x7fffu + ((c.u >> 16) & 1u);
  return (u16)((c.u + r) >> 16);
}

// ---------------------------------------------------------------- W^T (x3)
__global__ __launch_bounds__(256) void wtrans3_kernel(
    const float* __restrict__ Wq, const float* __restrict__ Wk,
    const float* __restrict__ Wv, u16* __restrict__ dst) {
  __shared__ u16 tile[32][33];
  int z = blockIdx.z;
  const float* src = (z == 0) ? Wq : (z == 1) ? Wk : Wv;
  u16* d = dst + (size_t)z * HS_ * C_;
  int c0 = blockIdx.x * 32, r0 = blockIdx.y * 32;  // c over HS_, r over C_
  int tx = threadIdx.x, ty = threadIdx.y;          // block (32, 8)
#pragma unroll
  for (int i = 0; i < 4; ++i)
    tile[ty + 8 * i][tx] = f2bf(src[(size_t)(r0 + ty + 8 * i) * HS_ + (c0 + tx)]);
  __syncthreads();
#pragma unroll
  for (int i = 0; i < 4; ++i)
    d[(size_t)(c0 + ty + 8 * i) * C_ + (r0 + tx)] = tile[tx][ty + 8 * i];
}

// ---------------------------------------------------------------- QKV GEMM
#define GBM 128
#define GBK 64
#define NKT (C_ / GBK)
#define XP 72     // padded leading dim for staging tiles
#define TP 136    // padded leading dim for transpose buffer

__global__ __launch_bounds__(256, 2) void qkv_gemm_kernel(
    const float* __restrict__ X, const u16* __restrict__ WT3,
    u16* __restrict__ qkv, u16* __restrict__ vT) {
  // pool: double-buffered Xs/Ws (2 x (128+128) x 72 u16 = 72 KB);
  // z==2 epilogue reuses it as a [128][136] transpose buffer (34.8 KB).
  __shared__ u16 smem[2 * 2 * GBM * XP];
  u16 (*Xs)[GBM][XP] = (u16(*)[GBM][XP])smem;                    // [2][128][72]
  u16 (*Ws)[GBM][XP] = (u16(*)[GBM][XP])(smem + 2 * GBM * XP);   // [2][128][72]

  int z = blockIdx.y;
  const u16* Wt = WT3 + (size_t)z * HS_ * C_;
  int t = threadIdx.x;                     // 0..255, 4 waves
  int wv = t >> 6, lane = t & 63;
  int l15 = lane & 15, hi = lane >> 4;
  int wm = (wv & 1) * 64;                  // M half
  int wn = (wv >> 1) * 64;                 // N half
  size_t mbase = (size_t)blockIdx.x * GBM;

  // staging decomposition: 1024 ids = 128 rows x 8 chunks; 4 ids/thread
  int srow = t >> 3, sc = t & 7;           // base row 0..31, chunk 0..7
  const float* xrowp[4];
  const u16* wrowp[4];
#pragma unroll
  for (int i = 0; i < 4; ++i) {
    xrowp[i] = &X[(mbase + i * 32 + srow) * C_];
    wrowp[i] = &Wt[(size_t)(i * 32 + srow) * C_];
  }

  floatx4 acc[4][4];
#pragma unroll
  for (int i = 0; i < 4; ++i)
#pragma unroll
    for (int j = 0; j < 4; ++j) acc[i][j] = (floatx4){0.f, 0.f, 0.f, 0.f};

  floatx4 xreg[4][2];
  short8 wreg[4];

  // prefetch kt=0
  {
    int koff = sc * 8;
#pragma unroll
    for (int i = 0; i < 4; ++i) {
      xreg[i][0] = *(const floatx4*)&xrowp[i][koff];
      xreg[i][1] = *(const floatx4*)&xrowp[i][koff + 4];
      wreg[i] = *(const short8*)&wrowp[i][koff];
    }
  }
  // stage into buffer 0
#pragma unroll
  for (int i = 0; i < 4; ++i) {
    short8 xv;
#pragma unroll
    for (int j = 0; j < 4; ++j) {
      xv[j] = (short)f2bf(xreg[i][0][j]);
      xv[4 + j] = (short)f2bf(xreg[i][1][j]);
    }
    *(short8*)&Xs[0][i * 32 + srow][sc * 8] = xv;
    *(short8*)&Ws[0][i * 32 + srow][sc * 8] = wreg[i];
  }
  __syncthreads();

  for (int kt = 0; kt < NKT; ++kt) {
    int p = kt & 1;
    // issue next K-step's global loads; latency hides under MFMA phase
    if (kt + 1 < NKT) {
      int koff = (kt + 1) * GBK + sc * 8;
#pragma unroll
      for (int i = 0; i < 4; ++i) {
        xreg[i][0] = *(const floatx4*)&xrowp[i][koff];
        xreg[i][1] = *(const floatx4*)&xrowp[i][koff + 4];
        wreg[i] = *(const short8*)&wrowp[i][koff];
      }
    }

    // MFMA phase on buffer p: per ks, 8 ds_read_b128 feed 16 MFMA
#pragma unroll
    for (int ks = 0; ks < 2; ++ks) {
      short8 af[4], bf[4];
#pragma unroll
      for (int mt = 0; mt < 4; ++mt)
        af[mt] = *(const short8*)&Xs[p][wm + mt * 16 + l15][ks * 32 + hi * 8];
#pragma unroll
      for (int nt = 0; nt < 4; ++nt)
        bf[nt] = *(const short8*)&Ws[p][wn + nt * 16 + l15][ks * 32 + hi * 8];
#pragma unroll
      for (int mt = 0; mt < 4; ++mt)
#pragma unroll
        for (int nt = 0; nt < 4; ++nt)
          acc[mt][nt] = __builtin_amdgcn_mfma_f32_16x16x32_bf16(
              af[mt], bf[nt], acc[mt][nt], 0, 0, 0);
    }

    // stage prefetched regs into the other buffer
    if (kt + 1 < NKT) {
#pragma unroll
      for (int i = 0; i < 4; ++i) {
        short8 xv;
#pragma unroll
        for (int j = 0; j < 4; ++j) {
          xv[j] = (short)f2bf(xreg[i][0][j]);
          xv[4 + j] = (short)f2bf(xreg[i][1][j]);
        }
        *(short8*)&Xs[p ^ 1][i * 32 + srow][sc * 8] = xv;
        *(short8*)&Ws[p ^ 1][i * 32 + srow][sc * 8] = wreg[i];
      }
    }
    __syncthreads();
  }

  if (z != 2) {
    u16* outp = qkv + (size_t)z * ((size_t)B_ * T_ * HS_);
#pragma unroll
    for (int mt = 0; mt < 4; ++mt)
#pragma unroll
      for (int nt = 0; nt < 4; ++nt)
#pragma unroll
        for (int r = 0; r < 4; ++r) {
          size_t row = mbase + wm + mt * 16 + hi * 4 + r;
          int col = wn + nt * 16 + l15;
          outp[row * HS_ + col] = f2bf(acc[mt][nt][r]);
        }
  } else {
    // V^T epilogue: transpose the 128x128 tile in LDS, write vT rows.
    u16 (*Tb)[TP] = (u16(*)[TP])smem;      // [128][136], 34.8 KB
#pragma unroll
    for (int mt = 0; mt < 4; ++mt)
#pragma unroll
      for (int nt = 0; nt < 4; ++nt)
#pragma unroll
        for (int r = 0; r < 4; ++r)
          Tb[wn + nt * 16 + l15][wm + mt * 16 + hi * 4 + r] = f2bf(acc[mt][nt][r]);
    __syncthreads();
    int b = (int)(mbase >> 12);            // T_ = 4096
    int trow0 = (int)(mbase & (T_ - 1));
    u16* vb = vT + (size_t)b * HS_ * T_;
#pragma unroll
    for (int i = 0; i < 8; ++i) {
      int id = i * 256 + t;                // 2048 ids = 128 rows x 16 chunks
      int c = id >> 4, ch = id & 15;
      short8 v = *(const short8*)&Tb[c][ch * 8];
      *(short8*)&vb[(size_t)c * T_ + trow0 + ch * 8] = v;
    }
  }
}

// ---------------------------------------------------------------- flash core
#define BQ 64
#define BKV 64
#define CHUNK 16  // KV tiles per split-KV block (1024 keys)

// Shared body: processes kv tiles [kb0, kb1] for (b, qb). If WRITE_PARTIAL,
// writes unnormalized O + (m,l); else normalizes and writes fp32 out.
template <bool WRITE_PARTIAL>
static __device__ __forceinline__ void flash_body(
    const u16* __restrict__ q, const u16* __restrict__ k,
    const u16* __restrict__ vT, float* __restrict__ outO,
    float* __restrict__ Mp, float* __restrict__ Lp,
    int b, int qb, int kb0, int kb1, int slot) {
  __shared__ u16 Ks[BKV][136];
  __shared__ u16 Vs[144][72];   // rows 0..127: V^T tile; rows 128..143: ones (l-column)
  __shared__ u16 Ps[BQ][72];
  int t = threadIdx.x;
  int wv = t >> 6, lane = t & 63, l15 = lane & 15, hi = lane >> 4;

  const float sc = 0.08838834764831845f * 1.4426950408889634f;

  short8 qf[4];
  {
    const u16* qrow = q + (size_t)(b * T_ + qb * BQ + wv * 16 + l15) * HS_;
#pragma unroll
    for (int ks = 0; ks < 4; ++ks)
      qf[ks] = *(const short8*)(qrow + ks * 32 + hi * 8);
  }

  // ones rows for MFMA l-accumulation: rows 128..143, cols 0..63 used by PV.
  {
    int r = 128 + (t >> 4), c0 = (t & 15) * 4;
    const u16 one = 0x3F80;  // bf16 1.0
    Vs[r][c0] = one; Vs[r][c0 + 1] = one;
    Vs[r][c0 + 2] = one; Vs[r][c0 + 3] = one;
  }

  floatx4 of[9];  // of[0..7] = O; of[8] = l (row-sum column)
#pragma unroll
  for (int dt = 0; dt < 9; ++dt) of[dt] = (floatx4){0.f, 0.f, 0.f, 0.f};
  float m_run[4];
#pragma unroll
  for (int r = 0; r < 4; ++r) m_run[r] = -__builtin_inff();

  const u16* kbase = k + (size_t)b * T_ * HS_;
  const u16* vbase = vT + (size_t)b * HS_ * T_;

  // ---- register prefetch of tile kb0
  short8 kreg[4], vreg[4];
#pragma unroll
  for (int i = 0; i < 4; ++i) {
    int id = i * 256 + t;
    int n = id >> 4, ck = id & 15;
    kreg[i] = *(const short8*)&kbase[(size_t)(kb0 * BKV + n) * HS_ + ck * 8];
    int d = id >> 3, cv = id & 7;
    vreg[i] = *(const short8*)&vbase[(size_t)d * T_ + kb0 * BKV + cv * 8];
  }

  for (int kb = kb0; kb <= kb1; ++kb) {
    // write staged registers -> LDS (vmcnt wait inserted by compiler)
#pragma unroll
    for (int i = 0; i < 4; ++i) {
      int id = i * 256 + t;
      int n = id >> 4, ck = id & 15;
      *(short8*)&Ks[n][ck * 8] = kreg[i];
      int d = id >> 3, cv = id & 7;
      *(short8*)&Vs[d][cv * 8] = vreg[i];
    }
    __syncthreads();

    // issue next tile's global loads early; results not needed until next
    // loop top, so their latency hides under QK/softmax/PV below.
    if (kb < kb1) {
#pragma unroll
      for (int i = 0; i < 4; ++i) {
        int id = i * 256 + t;
        int n = id >> 4, ck = id & 15;
        kreg[i] = *(const short8*)&kbase[(size_t)((kb + 1) * BKV + n) * HS_ + ck * 8];
        int d = id >> 3, cv = id & 7;
        vreg[i] = *(const short8*)&vbase[(size_t)d * T_ + (kb + 1) * BKV + cv * 8];
      }
    }

    floatx4 sf[4];
#pragma unroll
    for (int nt = 0; nt < 4; ++nt) {
      floatx4 s = (floatx4){0.f, 0.f, 0.f, 0.f};
#pragma unroll
      for (int ks = 0; ks < 4; ++ks) {
        short8 bfrag = *(const short8*)&Ks[nt * 16 + l15][ks * 32 + hi * 8];
        s = __builtin_amdgcn_mfma_f32_16x16x32_bf16(qf[ks], bfrag, s, 0, 0, 0);
      }
      sf[nt] = s;
    }

    float sv[4][4];
    if (kb == qb) {
#pragma unroll
      for (int nt = 0; nt < 4; ++nt) {
        int col = nt * 16 + l15;
#pragma unroll
        for (int r = 0; r < 4; ++r) {
          int row = wv * 16 + hi * 4 + r;
          sv[nt][r] = (col <= row) ? sf[nt][r] * sc : -__builtin_inff();
        }
      }
    } else {
#pragma unroll
      for (int nt = 0; nt < 4; ++nt)
#pragma unroll
        for (int r = 0; r < 4; ++r) sv[nt][r] = sf[nt][r] * sc;
    }

    // per-row max (4-step butterfly over the 16-lane group)
    float mt4[4];
#pragma unroll
    for (int r = 0; r < 4; ++r)
      mt4[r] = fmaxf(fmaxf(sv[0][r], sv[1][r]), fmaxf(sv[2][r], sv[3][r]));
#pragma unroll
    for (int off = 1; off < 16; off <<= 1)
#pragma unroll
      for (int r = 0; r < 4; ++r)
        mt4[r] = fmaxf(mt4[r], __shfl_xor(mt4[r], off));

    // defer-max: only rescale when a row max grew by > 8 (P bounded by 2^8)
    bool need = false;
#pragma unroll
    for (int r = 0; r < 4; ++r) need = need || (mt4[r] > m_run[r] + 8.f);
    if (__any(need)) {
      float alpha[4];
#pragma unroll
      for (int r = 0; r < 4; ++r) {
        float mn = fmaxf(m_run[r], mt4[r]);
        alpha[r] = exp2f(m_run[r] - mn);
        m_run[r] = mn;
      }
#pragma unroll
      for (int dt = 0; dt < 9; ++dt)
#pragma unroll
        for (int r = 0; r < 4; ++r) of[dt][r] *= alpha[r];
    }

    float pv[4][4];
#pragma unroll
    for (int nt = 0; nt < 4; ++nt)
#pragma unroll
      for (int r = 0; r < 4; ++r) pv[nt][r] = exp2f(sv[nt][r] - m_run[r]);

#pragma unroll
    for (int nt = 0; nt < 4; ++nt)
#pragma unroll
      for (int r = 0; r < 4; ++r)
        Ps[wv * 16 + hi * 4 + r][nt * 16 + l15] = f2bf(pv[nt][r]);
    __asm__ volatile("s_waitcnt lgkmcnt(0)" ::: "memory");

#pragma unroll
    for (int ks2 = 0; ks2 < 2; ++ks2) {
      short8 af = *(const short8*)&Ps[wv * 16 + l15][ks2 * 32 + hi * 8];
#pragma unroll
      for (int dt = 0; dt < 9; ++dt) {
        short8 bfrag = *(const short8*)&Vs[dt * 16 + l15][ks2 * 32 + hi * 8];
        of[dt] = __builtin_amdgcn_mfma_f32_16x16x32_bf16(af, bfrag, of[dt], 0, 0, 0);
      }
    }
    __syncthreads();
  }

  if (WRITE_PARTIAL) {
    float* Op = outO + (size_t)slot * (BQ * HS_);
#pragma unroll
    for (int dt = 0; dt < 8; ++dt)
#pragma unroll
      for (int r = 0; r < 4; ++r) {
        int row = wv * 16 + hi * 4 + r;
        Op[row * HS_ + dt * 16 + l15] = of[dt][r];
      }
    if (l15 == 0) {
#pragma unroll
      for (int r = 0; r < 4; ++r) {
        int row = wv * 16 + hi * 4 + r;
        Mp[slot * BQ + row] = m_run[r];
        Lp[slot * BQ + row] = of[8][r];  // l accumulated by MFMA ones-column
      }
    }
  } else {
    float rl[4];
#pragma unroll
    for (int r = 0; r < 4; ++r) rl[r] = 1.0f / of[8][r];
#pragma unroll
    for (int dt = 0; dt < 8; ++dt)
#pragma unroll
      for (int r = 0; r < 4; ++r) {
        size_t row = (size_t)(b * T_ + qb * BQ + wv * 16 + hi * 4 + r);
        outO[row * HS_ + dt * 16 + l15] = of[dt][r] * rl[r];
      }
  }
}

// split-KV partial: grid (64 qb, 4 chunk, 4 batch)
__global__ __launch_bounds__(256, 3) void flash_partial_kernel(
    const u16* __restrict__ q, const u16* __restrict__ k,
    const u16* __restrict__ vT, float* __restrict__ Opart,
    float* __restrict__ Mpart, float* __restrict__ Lpart) {
  int qb = blockIdx.x, c = blockIdx.y, b = blockIdx.z;
  int kb0 = c * CHUNK;
  if (kb0 > qb) return;  // empty chunk
  int kb1 = min(qb, kb0 + CHUNK - 1);
  int slot = (b * (T_ / BQ) + qb) * 4 + c;
  flash_body<true>(q, k, vT, Opart, Mpart, Lpart, b, qb, kb0, kb1, slot);
}

// monolithic fallback: grid (64 qb, 4 batch)
__global__ __launch_bounds__(256, 3) void flash_attn_kernel(
    const u16* __restrict__ q, const u16* __restrict__ k,
    const u16* __restrict__ vT, float* __restrict__ out) {
  int qb = blockIdx.x, b = blockIdx.y;
  flash_body<false>(q, k, vT, out, nullptr, nullptr, b, qb, 0, qb, 0);
}

// merge: grid (64 qb, 4 batch), 256 threads
__global__ __launch_bounds__(256) void flash_merge_kernel(
    const float* __restrict__ Opart, const float* __restrict__ Mpart,
    const float* __restrict__ Lpart, float* __restrict__ out) {
  __shared__ float w[4][BQ];
  __shared__ float invL[BQ];
  int qb = blockIdx.x, b = blockIdx.y;
  int t = threadIdx.x;
  int nch = qb / CHUNK + 1;  // 1..4
  int slot0 = (b * (T_ / BQ) + qb) * 4;

  if (t < BQ) {
    float mv[4], mmax = -__builtin_inff();
    for (int c = 0; c < nch; ++c) {
      mv[c] = Mpart[(slot0 + c) * BQ + t];
      mmax = fmaxf(mmax, mv[c]);
    }
    float L = 0.f;
    for (int c = 0; c < nch; ++c) {
      float wc = exp2f(mv[c] - mmax);
      w[c][t] = wc;
      L += wc * Lpart[(slot0 + c) * BQ + t];
    }
    invL[t] = 1.0f / L;
  }
  __syncthreads();

  size_t obase = ((size_t)(b * T_) + (size_t)qb * BQ) * HS_;
#pragma unroll
  for (int j = 0; j < 32; ++j) {
    int e = j * 256 + t;           // 0..8191
    int row = e >> 7;
    float acc = 0.f;
    for (int c = 0; c < nch; ++c)
      acc += w[c][row] * Opart[(size_t)(slot0 + c) * (BQ * HS_) + e];
    out[obase + e] = acc * invL[row];
  }
}

// ---------------------------------------------------------------- launch
extern "C" void kernel_launch(void* const* d_in, const int* in_sizes, int n_in,
                              void* d_out, int out_size, void* d_ws, size_t ws_size,
                              hipStream_t stream) {
  const float* x  = (const float*)d_in[0];
  const float* Wq = (const float*)d_in[1];
  const float* Wk = (const float*)d_in[2];
  const float* Wv = (const float*)d_in[3];
  float* out = (float*)d_out;

  u16* ws = (u16*)d_ws;
  const size_t wtsz  = (size_t)HS_ * C_;
  const size_t qkvsz = (size_t)B_ * T_ * HS_;
  u16* WT = ws;
  u16* qv = WT + 3 * wtsz;
  u16* kv = qv + qkvsz;
  u16* vT = kv + qkvsz;
  const size_t base_bytes = (3 * wtsz + 3 * qkvsz) * sizeof(u16);  // 14,155,776

  const int NSLOT = B_ * (T_ / BQ) * 4;  // 1024
  float* Opart = (float*)((char*)d_ws + base_bytes);
  float* Mpart = Opart + (size_t)NSLOT * BQ * HS_;
  float* Lpart = Mpart + (size_t)NSLOT * BQ;
  const size_t split_bytes =
      base_bytes + ((size_t)NSLOT * BQ * HS_ + 2 * (size_t)NSLOT * BQ) * sizeof(float);

  dim3 tb(32, 8);
  wtrans3_kernel<<<dim3(HS_ / 32, C_ / 32, 3), tb, 0, stream>>>(Wq, Wk, Wv, WT);

  qkv_gemm_kernel<<<dim3((B_ * T_) / GBM, 3), 256, 0, stream>>>(x, WT, qv, vT);

  if (ws_size >= split_bytes) {
    flash_partial_kernel<<<dim3(T_ / BQ, 4, B_), 256, 0, stream>>>(
        qv, kv, vT, Opart, Mpart, Lpart);
    flash_merge_kernel<<<dim3(T_ / BQ, B_), 256, 0, stream>>>(
        Opart, Mpart, Lpart, out);
  } else {
    flash_attn_kernel<<<dim3(T_ / BQ, B_), 256, 0, stream>>>(qv, kv, vT, out);
  }
}